// Round 9
// baseline (143.489 us; speedup 1.0000x reference)
//
#include <hip/hip_runtime.h>
#include <hip/hip_bf16.h>

// Problem constants
#define NB  2      // batch
#define CC  256    // channels
#define NHD 8      // heads
#define HD  32     // head dim
#define NT  4096   // tokens = H*W

typedef __bf16 bf16x8 __attribute__((ext_vector_type(8)));
typedef bf16x8 bf16x8_ma __attribute__((may_alias));
typedef __bf16 bf16x4 __attribute__((ext_vector_type(4)));
typedef bf16x4 bf16x4_ma __attribute__((may_alias));
typedef float  f32x4  __attribute__((ext_vector_type(4)));
typedef f32x4  f32x4_ma __attribute__((may_alias));
typedef float  f32x16 __attribute__((ext_vector_type(16)));
typedef unsigned int u32x4 __attribute__((ext_vector_type(4)));
typedef unsigned short u16x8 __attribute__((ext_vector_type(8)));

static __device__ __forceinline__ f32x4 zero4() {
    f32x4 z = {0.f, 0.f, 0.f, 0.f}; return z;
}
static __device__ __forceinline__ f32x16 zero16() {
    f32x16 z = {0.f,0.f,0.f,0.f,0.f,0.f,0.f,0.f,
                0.f,0.f,0.f,0.f,0.f,0.f,0.f,0.f};
    return z;
}

// q pre-scale: log2(e) / sqrt(32)
#define QSCALE 0.25505392421795654f

// v_cvt_pk_bf16_f32: dst.lo = bf16(lo), dst.hi = bf16(hi)  (no builtin on gfx950)
#define CVT_PK(dst, lo, hi_) \
    asm("v_cvt_pk_bf16_f32 %0, %1, %2" : "=v"(dst) : "v"(lo), "v"(hi_))
// v_permlane32_swap_b32: x[32:63] <-> y[0:31]
#define PLSWAP(x, y) \
    asm("v_permlane32_swap_b32 %0, %1" : "+v"(x), "+v"(y))

// ---------------------------------------------------------------------------
// ROUND 26: attn is VALU-issue-bound (R25: VALUBusy 50% = 29us of issue at
// 58.6us). Remove the softmax row-sum from the VALU entirely: l is computed
// on the MFMA pipe (23% util) as lacc = mfma(ap, ones_B) -- P row-sums land
// replicated across columns in EXACTLY oacc's register layout, so the
// epilogue is a pointwise oacc[i]/lacc[i]. Deleted per subtile: 16 f32 adds;
// deleted at end: cross-lane reduce + llds. Numerics: l now sums the same
// bf16(p) values PV consumes (was f32 p) -- self-consistent, ~1 ulp shift.
// qkv/proj LDS-share, JSEG=2 j-split, comb_k: unchanged (proven R25).
// ---------------------------------------------------------------------------

// ---------------------------------------------------------------------------
// Kernel 0: f32 -> bf16 convert, both weight arrays in one launch.
// ---------------------------------------------------------------------------
__global__ __launch_bounds__(256) void convw_k(const float* __restrict__ s1,
                                               __bf16* __restrict__ d1, int n1,
                                               const float* __restrict__ s2,
                                               __bf16* __restrict__ d2, int n2) {
    const int i = blockIdx.x * 256 + threadIdx.x;
    if (i < n1) d1[i] = (__bf16)s1[i];
    else if (i - n1 < n2) d2[i - n1] = (__bf16)s2[i - n1];
}

// ---------------------------------------------------------------------------
// Kernel 1: LDS-tiled transpose+convert x f32 [b][c][n] -> xt bf16 [b][n][c].
// ---------------------------------------------------------------------------
__global__ __launch_bounds__(256) void transpose_k(const float* __restrict__ x,
                                                   __bf16* __restrict__ xt) {
    __shared__ __bf16 T[64][65];
    const int tid = threadIdx.x;
    const int n0 = blockIdx.x * 64, c0 = blockIdx.y * 64, b = blockIdx.z;

#pragma unroll
    for (int rep = 0; rep < 16; ++rep) {
        const int e = rep * 256 + tid;
        const int cl = e >> 6, nl = e & 63;
        T[nl][cl] = (__bf16)x[((size_t)(b * CC + c0 + cl)) * NT + n0 + nl];
    }
    __syncthreads();
#pragma unroll
    for (int rep = 0; rep < 16; ++rep) {
        const int e = rep * 256 + tid;
        const int nl = e >> 6, cl = e & 63;
        xt[((size_t)(b * NT + n0 + nl)) * CC + c0 + cl] = T[nl][cl];
    }
}

// ---------------------------------------------------------------------------
// Kernel 2: QKV GEMM (MFMA), B-tile LDS-shared (proven R24).
// grid (NT/64, 768/64, NB), block 256.
// ---------------------------------------------------------------------------
__global__ __launch_bounds__(256) void qkv_k(const __bf16* __restrict__ wqkv,
                                             const __bf16* __restrict__ xt,
                                             __bf16* __restrict__ qt,
                                             __bf16* __restrict__ kt,
                                             __bf16* __restrict__ vv) {
    __shared__ __align__(16) __bf16 BF[4][8][512];   // [js][kc][lane*8] 32 KB

    const int lane = threadIdx.x & 63, wv = threadIdx.x >> 6;
    const int g = lane >> 4, c16 = lane & 15;
    const int b    = blockIdx.z;
    const int o0   = blockIdx.y * 64 + wv * 16;
    const int tok0 = blockIdx.x * 64;

    // Stage B-tile: wave wv stages js=wv, kc=0..7 (1 KB chunks, lane-order).
    const __bf16* bsrc = xt + ((size_t)(b * NT + tok0 + wv * 16 + c16)) * CC + g * 8;
#pragma unroll
    for (int kc = 0; kc < 8; ++kc) {
        __builtin_amdgcn_global_load_lds(
            (const __attribute__((address_space(1))) void*)(bsrc + kc * 32),
            (__attribute__((address_space(3))) void*)&BF[wv][kc][0],
            16, 0, 0);
    }

    // Preload A rows (o0+c16, all 8 k-chunks) while the stage is in flight.
    const __bf16* arow = wqkv + (size_t)(o0 + c16) * CC + g * 8;
    bf16x8 a[8];
#pragma unroll
    for (int kc = 0; kc < 8; ++kc) a[kc] = *(const bf16x8_ma*)(arow + kc * 32);

    __syncthreads();   // drains vmcnt(0): stage + A-loads complete

    f32x4 acc[4];
#pragma unroll
    for (int i = 0; i < 4; ++i) acc[i] = zero4();

#pragma unroll
    for (int kc = 0; kc < 8; ++kc) {
#pragma unroll
        for (int js = 0; js < 4; ++js) {
            bf16x8 bb = *(const bf16x8_ma*)&BF[js][kc][lane * 8];
            acc[js] = __builtin_amdgcn_mfma_f32_16x16x32_bf16(a[kc], bb, acc[js], 0, 0, 0);
        }
    }

    const int reg = o0 >> 8;                 // 0=q, 1=k, 2=v (wave-uniform)
    const int oo0 = (o0 & 255) + g * 4;
    const int h   = oo0 >> 5;
    const int dd0 = oo0 & 31;
    const size_t bh = (size_t)(b * NHD + h);

#pragma unroll
    for (int js = 0; js < 4; ++js) {
        const int tok = tok0 + js * 16 + c16;
        if (reg == 0) {
            bf16x4 pk;
#pragma unroll
            for (int r = 0; r < 4; ++r) pk[r] = (__bf16)(acc[js][r] * QSCALE);
            *(bf16x4_ma*)(qt + (bh * NT + tok) * HD + dd0) = pk;
        } else if (reg == 1) {
            bf16x4 pk;
#pragma unroll
            for (int r = 0; r < 4; ++r) pk[r] = (__bf16)acc[js][r];
            *(bf16x4_ma*)(kt + (bh * NT + tok) * HD + dd0) = pk;
        } else {
#pragma unroll
            for (int r = 0; r < 4; ++r)
                vv[(bh * HD + dd0 + r) * NT + tok] = (__bf16)acc[js][r];
        }
    }
}

// ---------------------------------------------------------------------------
// Kernel 3: MFMA flash attention, 32x32 swapped-operand, in-register P,
// block-shared LDS K/V (R22 loop), l computed on the MFMA pipe (ones-B).
// Block 256 thr = 4 waves x 32 queries = 128 q/block; block sweeps the
// j-range of its gridDim.z segment (seg = blockIdx.z).
// Per 32-j subtile: 4 ds_read_b128, 2 QK^T MFMAs, 16 exp2, 8 cvt_pk,
// 4 permlane, 2 PV MFMAs, 2 ones-MFMAs (lacc). Zero VALU adds for l.
// JSEG=2: writes f32 partial (O,l) to PO/PL; JSEG=1: writes ao directly.
// grid (NT/128, NB*NHD, JSEG), LDS 16KB.
// ---------------------------------------------------------------------------
__global__ __launch_bounds__(256, 4) void attn_k(const __bf16* __restrict__ qt,
                                                 const __bf16* __restrict__ kt,
                                                 const __bf16* __restrict__ vv,
                                                 __bf16* __restrict__ ao,
                                                 float* __restrict__ PO,
                                                 float* __restrict__ PL) {
    // Fragment lane-order tiles: [buf][js][half][lane*8 bf16]
    __shared__ __align__(16) __bf16 KF[2][2][2][512];   // 8 KB
    __shared__ __align__(16) __bf16 VF[2][2][2][512];   // 8 KB

    const int tid  = threadIdx.x;
    const int lane = tid & 63, wv = tid >> 6;          // wv 0..3
    const int c32 = lane & 31, hi = lane >> 5;
    const int bh = blockIdx.y;
    const int b = bh >> 3, h = bh & 7;
    const int seg = blockIdx.z, nseg = gridDim.z;
    const int i0q = blockIdx.x * 128 + wv * 32;        // this wave: 32 queries

    const __bf16* qbase = qt + ((size_t)bh * NT + i0q) * HD;
    const __bf16* kbase = kt + (size_t)bh * NT * HD;
    const __bf16* vbase = vv + (size_t)bh * HD * NT;

    // Staging role of this wave: K chunk (stg_js, kk=stg_sl), V chunk (stg_js, vslot=stg_sl)
    const int stg_js = wv & 1, stg_sl = wv >> 1;

    // Q fragments (B operand of score MFMA): row=q=c32, k = kk*16 + hi*8 + e
    bf16x8 aq0 = *(const bf16x8_ma*)(qbase + (size_t)c32 * HD + hi * 8);
    bf16x8 aq1 = *(const bf16x8_ma*)(qbase + (size_t)c32 * HD + 16 + hi * 8);

    // All-ones bf16 B operand (layout-independent: every element is 1.0).
    u16x8 ones_u = {0x3F80,0x3F80,0x3F80,0x3F80,0x3F80,0x3F80,0x3F80,0x3F80};
    const bf16x8 ones = __builtin_bit_cast(bf16x8, ones_u);

    f32x16 oacc = zero16();      // D[q_row][d_col]: rows=q, cols=d=c32
    f32x16 lacc = zero16();      // row-sums of P, replicated across cols

#define STAGE(bf, jb) do {                                                              \
    const __bf16* gk = kbase + (size_t)((jb) + stg_js * 32 + c32) * HD                  \
                             + stg_sl * 16 + hi * 8;                                    \
    __builtin_amdgcn_global_load_lds(                                                   \
        (const __attribute__((address_space(1))) void*)gk,                              \
        (__attribute__((address_space(3))) void*)&KF[bf][stg_js][stg_sl][0],            \
        16, 0, 0);                                                                      \
    const __bf16* gv = vbase + (size_t)c32 * NT + (jb) + stg_js * 32                    \
                             + stg_sl * 16 + hi * 8;                                    \
    __builtin_amdgcn_global_load_lds(                                                   \
        (const __attribute__((address_space(1))) void*)gv,                              \
        (__attribute__((address_space(3))) void*)&VF[bf][stg_js][stg_sl][0],            \
        16, 0, 0);                                                                      \
} while (0)

#define SUBTILE(bf, js) do {                                                            \
    bf16x8 fk0 = *(const bf16x8_ma*)&KF[bf][js][0][lane * 8];                           \
    bf16x8 fk1 = *(const bf16x8_ma*)&KF[bf][js][1][lane * 8];                           \
    bf16x8 fv0 = *(const bf16x8_ma*)&VF[bf][js][0][lane * 8];                           \
    bf16x8 fv1 = *(const bf16x8_ma*)&VF[bf][js][1][lane * 8];                           \
    f32x16 s = __builtin_amdgcn_mfma_f32_32x32x16_bf16(fk0, aq0, zero16(), 0, 0, 0);    \
    s = __builtin_amdgcn_mfma_f32_32x32x16_bf16(fk1, aq1, s, 0, 0, 0);                  \
    float p[16];                                                                        \
    _Pragma("unroll")                                                                   \
    for (int r = 0; r < 16; ++r) p[r] = __builtin_amdgcn_exp2f(s[r]);                   \
    unsigned pk[8];                                                                     \
    _Pragma("unroll")                                                                   \
    for (int i = 0; i < 8; ++i) CVT_PK(pk[i], p[2 * i], p[2 * i + 1]);                  \
    PLSWAP(pk[0], pk[2]);                                                               \
    PLSWAP(pk[1], pk[3]);                                                               \
    PLSWAP(pk[4], pk[6]);                                                               \
    PLSWAP(pk[5], pk[7]);                                                               \
    u32x4 a0 = {pk[0], pk[1], pk[2], pk[3]};                                            \
    u32x4 a1 = {pk[4], pk[5], pk[6], pk[7]};                                            \
    const bf16x8 ap0 = __builtin_bit_cast(bf16x8, a0);                                  \
    const bf16x8 ap1 = __builtin_bit_cast(bf16x8, a1);                                  \
    oacc = __builtin_amdgcn_mfma_f32_32x32x16_bf16(ap0, fv0, oacc, 0, 0, 0);            \
    oacc = __builtin_amdgcn_mfma_f32_32x32x16_bf16(ap1, fv1, oacc, 0, 0, 0);            \
    lacc = __builtin_amdgcn_mfma_f32_32x32x16_bf16(ap0, ones, lacc, 0, 0, 0);           \
    lacc = __builtin_amdgcn_mfma_f32_32x32x16_bf16(ap1, ones, lacc, 0, 0, 0);           \
} while (0)

    const int ntiles  = (NT / 64) / nseg;          // 64 (jseg=1) or 32 (jseg=2)
    const int j_begin = seg * ntiles * 64;

    // Prologue: stage tile 0 into buf 0.
    STAGE(0, j_begin);
    asm volatile("s_waitcnt vmcnt(0)" ::: "memory");
    __syncthreads();

    int buf = 0;
#pragma unroll 1
    for (int t = 0; t < ntiles; ++t) {
        if (t + 1 < ntiles) STAGE(buf ^ 1, j_begin + (t + 1) * 64);
        SUBTILE(buf, 0);
        SUBTILE(buf, 1);
        asm volatile("s_waitcnt vmcnt(0)" ::: "memory");
        __syncthreads();
        buf ^= 1;
    }

#undef STAGE
#undef SUBTILE

    if (nseg == 1) {
        // Direct epilogue: oacc/lacc rows q = 8*g4 + 4*hi + r, cols d = c32.
#pragma unroll
        for (int g4 = 0; g4 < 4; ++g4) {
#pragma unroll
            for (int r = 0; r < 4; ++r) {
                const int q = 8 * g4 + 4 * hi + r;
                ao[((size_t)(b * NT) + i0q + q) * CC + h * HD + c32] =
                    (__bf16)(oacc[4 * g4 + r] / lacc[4 * g4 + r]);
            }
        }
    } else {
        // Partial epilogue: PO [seg][bh][n][32] f32, PL [seg][bh][n] f32.
        float* po = PO + (((size_t)seg * NB * NHD + bh) * NT + i0q) * HD;
#pragma unroll
        for (int g4 = 0; g4 < 4; ++g4) {
#pragma unroll
            for (int r = 0; r < 4; ++r) {
                const int q = 8 * g4 + 4 * hi + r;
                po[(size_t)q * HD + c32] = oacc[4 * g4 + r];
            }
        }
        if (c32 == 0) {
            float* pl = PL + ((size_t)seg * NB * NHD + bh) * NT + i0q;
#pragma unroll
            for (int g4 = 0; g4 < 4; ++g4)
#pragma unroll
                for (int r = 0; r < 4; ++r)
                    pl[8 * g4 + 4 * hi + r] = lacc[4 * g4 + r];
        }
    }
}

// ---------------------------------------------------------------------------
// Kernel 3b: combine JSEG=2 partials: ao = (O0+O1)/(l0+l1), bf16.
// One thread = 4 consecutive d of one (bh, n). grid 2048 x 256.
// ---------------------------------------------------------------------------
__global__ __launch_bounds__(256) void comb_k(const float* __restrict__ PO,
                                              const float* __restrict__ PL,
                                              __bf16* __restrict__ ao) {
    const int i = blockIdx.x * 256 + threadIdx.x;    // 0 .. 16*4096*8-1
    const int bh = i >> 15;                          // 8 groups * 4096 n
    const int rem = i & 32767;
    const int n = rem >> 3, g = rem & 7;
    const int b = bh >> 3, h = bh & 7;

    const size_t o0i = (((size_t)bh) * NT + n) * HD + g * 4;
    const size_t o1i = o0i + (size_t)(NB * NHD) * NT * HD;
    f32x4 o0 = *(const f32x4_ma*)&PO[o0i];
    f32x4 o1 = *(const f32x4_ma*)&PO[o1i];
    const float l = PL[(size_t)bh * NT + n] + PL[(size_t)(NB * NHD) * NT + (size_t)bh * NT + n];

    bf16x4 pk;
#pragma unroll
    for (int r = 0; r < 4; ++r) pk[r] = (__bf16)((o0[r] + o1[r]) / l);
    *(bf16x4_ma*)&ao[((size_t)(b * NT) + n) * CC + h * HD + g * 4] = pk;
}

// ---------------------------------------------------------------------------
// Kernel 4: proj GEMM + residual (MFMA), F32 output, B-tile LDS-shared.
// grid (NT/64, CC/64, NB), block 256.
// ---------------------------------------------------------------------------
__global__ __launch_bounds__(256) void proj_k(const __bf16* __restrict__ wp,
                                              const __bf16* __restrict__ ao,
                                              const float* __restrict__ x,
                                              float* __restrict__ out) {
    __shared__ __align__(16) __bf16 BF[4][8][512];   // [js][kc][lane*8] 32 KB

    const int lane = threadIdx.x & 63, wv = threadIdx.x >> 6;
    const int g = lane >> 4, c16 = lane & 15;
    const int b    = blockIdx.z;
    const int o0   = blockIdx.y * 64 + wv * 16;
    const int tok0 = blockIdx.x * 64;

    // Stage B-tile (ao rows) once per block, fragment lane-order.
    const __bf16* bsrc = ao + ((size_t)(b * NT + tok0 + wv * 16 + c16)) * CC + g * 8;
#pragma unroll
    for (int kc = 0; kc < 8; ++kc) {
        __builtin_amdgcn_global_load_lds(
            (const __attribute__((address_space(1))) void*)(bsrc + kc * 32),
            (__attribute__((address_space(3))) void*)&BF[wv][kc][0],
            16, 0, 0);
    }

    const __bf16* arow = wp + (size_t)(o0 + c16) * CC + g * 8;
    bf16x8 a[8];
#pragma unroll
    for (int kc = 0; kc < 8; ++kc) a[kc] = *(const bf16x8_ma*)(arow + kc * 32);

    __syncthreads();

    f32x4 acc[4];
#pragma unroll
    for (int i = 0; i < 4; ++i) acc[i] = zero4();

#pragma unroll
    for (int kc = 0; kc < 8; ++kc) {
#pragma unroll
        for (int js = 0; js < 4; ++js) {
            bf16x8 bb = *(const bf16x8_ma*)&BF[js][kc][lane * 8];
            acc[js] = __builtin_amdgcn_mfma_f32_16x16x32_bf16(a[kc], bb, acc[js], 0, 0, 0);
        }
    }

#pragma unroll
    for (int js = 0; js < 4; ++js) {
        const int tok = tok0 + js * 16 + c16;
#pragma unroll
        for (int r = 0; r < 4; ++r) {
            const int o = o0 + g * 4 + r;
            const size_t idx = ((size_t)(b * CC + o)) * NT + tok;
            out[idx] = acc[js][r] + x[idx];
        }
    }
}

// ---------------------------------------------------------------------------
extern "C" void kernel_launch(void* const* d_in, const int* in_sizes, int n_in,
                              void* d_out, int out_size, void* d_ws, size_t ws_size,
                              hipStream_t stream) {
    const int SX  = NB * CC * NT;   // 2,097,152
    const int SW3 = 3 * CC * CC;    //   196,608
    const int SW1 = CC * CC;        //    65,536
    const size_t E = (size_t)SX;

    const float* x  = nullptr;
    const float* wq = nullptr;
    const float* wp = nullptr;
    for (int i = 0; i < n_in; ++i) {
        const int sz = in_sizes[i];
        if (sz == SX || sz == 2 * SX || sz == 4 * SX)           x  = (const float*)d_in[i];
        else if (sz == SW3 || sz == 2 * SW3 || sz == 4 * SW3)   wq = (const float*)d_in[i];
        else if (sz == SW1 || sz == 2 * SW1 || sz == 4 * SW1)   wp = (const float*)d_in[i];
    }
    if (!x || !wq || !wp) {
        x  = (const float*)d_in[0];
        wq = (const float*)d_in[1];
        wp = (const float*)d_in[2];
    }

    // Workspace (bf16 elements), base 17.3 MB (proven):
    __bf16* ws  = (__bf16*)d_ws;
    __bf16* wqb = ws;
    __bf16* wpb = wqb + SW3;
    __bf16* xt  = wpb + SW1;             // becomes ao after qkv_k
    __bf16* qt  = xt + E;
    __bf16* kt  = qt + E;
    __bf16* vv  = kt + E;
    __bf16* ao  = xt;

    // Optional JSEG=2 partial buffers (f32), appended after vv:
    const size_t baseB = (size_t)(SW3 + SW1) * 2 + 4 * E * 2;       // bytes used
    const size_t poB   = 2ull * NB * NHD * NT * HD * 4;             // 16.78 MB
    const size_t plB   = 2ull * NB * NHD * NT * 4;                  //  0.52 MB
    const int jseg = (ws_size >= baseB + poB + plB) ? 2 : 1;
    float* PO = (float*)((char*)d_ws + baseB);
    float* PL = (float*)((char*)d_ws + baseB + poB);

    float* out = (float*)d_out;

    convw_k<<<dim3((SW3 + SW1 + 255) / 256), 256, 0, stream>>>(wq, wqb, SW3, wp, wpb, SW1);
    transpose_k<<<dim3(NT / 64, CC / 64, NB), 256, 0, stream>>>(x, xt);
    qkv_k<<<dim3(NT / 64, (3 * CC) / 64, NB), 256, 0, stream>>>(wqb, xt, qt, kt, vv);
    attn_k<<<dim3(NT / 128, NB * NHD, jseg), 256, 0, stream>>>(qt, kt, vv, ao, PO, PL);
    if (jseg == 2)
        comb_k<<<dim3((NB * NHD * NT * (HD / 4)) / 256), 256, 0, stream>>>(PO, PL, ao);
    proj_k<<<dim3(NT / 64, CC / 64, NB), 256, 0, stream>>>(wpb, ao, x, out);
}